// Round 8
// baseline (146.571 us; speedup 1.0000x reference)
//
#include <hip/hip_runtime.h>

// multi_triples_lstm v8: barrier-free ILP design. 1024 single-wave WGs
// (1 wave/SIMD), each wave owns TWO independent 16-batch chains (32 batches)
// with v4's fully in-register recurrence (row-permuted W so each lane's MFMA
// D-outputs are exactly its next B-fragment h-units) and v7's
// shared-denominator activation algebra (7 trans/unit-step). While chain A's
// serial dependency chain stalls, chain B's instructions issue -> per-wave
// ILP replaces the convoy-prone cross-wave TLP of v5-v7. No barriers, no
// exchange. 512-VGPR budget keeps both chains + weights in registers.
//
// LDS (dynamic):
//   X0 @ 0     : 16 rows x 1040B (chain0 fp16 feats; (b,t) at b*1040+t*32)
//   X1 @ 16640 : 16 rows x 1040B (chain1)
//   Z  @ 33280 : 48B zeros (x-frag quads 2,3 + t=31 prefetch guard)
//   fc2 scratch overlays X (2 chains x 16 rows x 144B)
#define LDS_BYTES 33328

typedef _Float16 f16x8 __attribute__((ext_vector_type(8)));
typedef float    f32x4 __attribute__((ext_vector_type(4)));

#define LOG2E     1.44269504088896f
#define TWO_LOG2E 2.88539008177793f

__device__ __forceinline__ int pack2(float a, float b) {  // RTN fp16 pair
    union { _Float16 h[2]; int i; } u;
    u.h[0] = (_Float16)a; u.h[1] = (_Float16)b;
    return u.i;
}

__global__ __launch_bounds__(64, 1)
void lstm_fused(const int* __restrict__ objs,
                const float* __restrict__ boxes,
                const int* __restrict__ preds,
                const int* __restrict__ subj,
                const float* __restrict__ obj_emb,
                const float* __restrict__ pred_emb,
                const float* __restrict__ W_ih,
                const float* __restrict__ W_hh,
                const float* __restrict__ b_ih,
                const float* __restrict__ b_hh,
                const float* __restrict__ fc2_W,
                const float* __restrict__ fc2_b,
                float* __restrict__ out)
{
    extern __shared__ char smem[];
    const int tid  = threadIdx.x;        // == lane, one wave per block
    const int quad = tid >> 4;           // 0..3
    const int cidx = tid & 15;           // batch row index
    const int ZOFF = 33280;

    if (tid < 12) ((int*)(smem + ZOFF))[tid] = 0;

    // ---- stage x features (fp16): 2 chains x 16 b x 32 t; lane = (row, t-half)
    {
        int row = tid >> 1;              // 0..31 = ch*16 + b
        int ch  = row >> 4;
        int b   = row & 15;
        int t0  = (tid & 1) << 4;        // 0 or 16
        long gb = (long)blockIdx.x * 32 + row;
        const int* op = objs  + gb * 32 + t0;
        const int* pp = preds + gb * 32 + t0;
        const int* sp = subj  + gb * 32 + t0;
        char* base = smem + ch * 16640 + b * 1040;
        #pragma unroll
        for (int c4 = 0; c4 < 16; c4 += 4) {
            int4 ov = *(const int4*)(op + c4);
            int4 pv = *(const int4*)(pp + c4);
            int4 sv = *(const int4*)(sp + c4);
            int oarr[4] = {ov.x, ov.y, ov.z, ov.w};
            int parr[4] = {pv.x, pv.y, pv.z, pv.w};
            int sarr[4] = {sv.x, sv.y, sv.z, sv.w};
            #pragma unroll
            for (int tt = 0; tt < 4; ++tt) {
                int t = t0 + c4 + tt;
                const float* eo = obj_emb  + oarr[tt] * 5;
                const float* ep = pred_emb + parr[tt] * 5;
                float4 bx = *(const float4*)(boxes + (gb * 32 + t) * 4);
                f16x8 lo, hi;
                lo[0]=(_Float16)eo[0]; lo[1]=(_Float16)eo[1]; lo[2]=(_Float16)eo[2];
                lo[3]=(_Float16)eo[3]; lo[4]=(_Float16)eo[4];
                lo[5]=(_Float16)ep[0]; lo[6]=(_Float16)ep[1]; lo[7]=(_Float16)ep[2];
                hi[0]=(_Float16)ep[3]; hi[1]=(_Float16)ep[4];
                hi[2]=(_Float16)(sarr[tt]==0 ? 1.0f : 0.0f);
                hi[3]=(_Float16)(sarr[tt]==1 ? 1.0f : 0.0f);
                hi[4]=(_Float16)bx.x; hi[5]=(_Float16)bx.y;
                hi[6]=(_Float16)bx.z; hi[7]=(_Float16)bx.w;
                char* dst = base + t * 32;
                *(f16x8*)dst        = lo;
                *(f16x8*)(dst + 16) = hi;
            }
        }
    }

    // ---- W fragments (shared by both chains), v4 row permutation ----
    // tile j = 2g+half (g: 0=i,1=f,2=g,3=o). Tile-row m <-> unit
    // u(m) = 8*(m>>2) + (m&3) + 4*half. A-frag: m=cidx, k=quad*8+jj over
    // K=[x16|pad16|h32]. Lane's D rows (m=4q+r) = units {8q+r+4*half} =
    // exactly its next B-frag slots. Scales folded (i/f/o: -log2e, g: +2log2e).
    f16x8 Wf[8][2];
    f32x4 bias4[8];
    #pragma unroll
    for (int j = 0; j < 8; ++j) {
        int g = j >> 1, half = j & 1;
        float scale = (g == 2) ? TWO_LOG2E : -LOG2E;
        int um = 8 * (cidx >> 2) + (cidx & 3) + 4 * half;
        int n  = g * 32 + um;
        #pragma unroll
        for (int ks = 0; ks < 2; ++ks) {
            f16x8 v;
            #pragma unroll
            for (int jj = 0; jj < 8; ++jj) {
                int k = ks * 32 + quad * 8 + jj;
                float val = (k < 16) ? W_ih[n * 16 + k]
                          : (k >= 32) ? W_hh[n * 32 + (k - 32)]
                          : 0.0f;
                v[jj] = (_Float16)(val * scale);
            }
            Wf[j][ks] = v;
        }
        #pragma unroll
        for (int r = 0; r < 4; ++r) {
            int ur = 8 * quad + r + 4 * half;
            bias4[j][r] = (b_ih[g * 32 + ur] + b_hh[g * 32 + ur]) * scale;
        }
    }

    // ---- x B-frag addressing (kstep0: quads 0,1 = x, quads 2,3 = zeros) ----
    const bool qlow = (quad < 2);
    int xaddr[2];
    xaddr[0] = qlow ? (0     + cidx * 1040 + quad * 16) : ZOFF;
    xaddr[1] = qlow ? (16640 + cidx * 1040 + quad * 16) : ZOFF;
    const int xinc = qlow ? 32 : 0;

    __syncthreads();   // single wave: orders staging writes vs reads

    // prime both chains: x[0] MFMAs (bias rides as C); h(0)=c(0)=0
    f32x4 accp[2][8];
    #pragma unroll
    for (int ch = 0; ch < 2; ++ch) {
        f16x8 xf = *(const f16x8*)(smem + xaddr[ch]); xaddr[ch] += xinc;
        #pragma unroll
        for (int j = 0; j < 8; ++j)
            accp[ch][j] = __builtin_amdgcn_mfma_f32_16x16x32_f16(Wf[j][0], xf, bias4[j], 0, 0, 0);
    }

    int   pk[2][4] = {{0,0,0,0},{0,0,0,0}};
    float cst[2][8] = {{0,0,0,0,0,0,0,0},{0,0,0,0,0,0,0,0}};
    float hlo[2][4], hhi[2][4];

    for (int t = 0; t < 32; ++t) {
        // h-MFMAs, both chains back-to-back (fills MFMA pipe, then both
        // activation streams interleave on VALU/trans)
        f32x4 acc[2][8];
        #pragma unroll
        for (int ch = 0; ch < 2; ++ch) {
            union { int i[4]; f16x8 v; } hf;
            hf.i[0] = pk[ch][0]; hf.i[1] = pk[ch][1];
            hf.i[2] = pk[ch][2]; hf.i[3] = pk[ch][3];
            #pragma unroll
            for (int j = 0; j < 8; ++j)
                acc[ch][j] = __builtin_amdgcn_mfma_f32_16x16x32_f16(Wf[j][1], hf.v, accp[ch][j], 0, 0, 0);
        }

        // prefetch next x for both chains (t=31 reads pad/Z — discarded)
        f16x8 xn0 = *(const f16x8*)(smem + xaddr[0]); xaddr[0] += xinc;
        f16x8 xn1 = *(const f16x8*)(smem + xaddr[1]); xaddr[1] += xinc;

        // activations (shared-denominator, 7 trans/unit), both chains
        #pragma unroll
        for (int ch = 0; ch < 2; ++ch) {
            #pragma unroll
            for (int r = 0; r < 4; ++r) {
                float Ei0 = __builtin_amdgcn_exp2f(acc[ch][0][r]);
                float Ei1 = __builtin_amdgcn_exp2f(acc[ch][1][r]);
                float Ef0 = __builtin_amdgcn_exp2f(acc[ch][2][r]);
                float Ef1 = __builtin_amdgcn_exp2f(acc[ch][3][r]);
                float Eg0 = __builtin_amdgcn_exp2f(acc[ch][4][r]);
                float Eg1 = __builtin_amdgcn_exp2f(acc[ch][5][r]);
                float Eo0 = __builtin_amdgcn_exp2f(acc[ch][6][r]);
                float Eo1 = __builtin_amdgcn_exp2f(acc[ch][7][r]);

                float t10  = 1.0f + Ei0;
                float t11  = 1.0f + Ei1;
                float dig0 = fmaf(t10, Eg0, t10);          // (1+Ei)(1+Eg)
                float dig1 = fmaf(t11, Eg1, t11);
                float tf0  = 1.0f + Ef0;
                float tf1  = 1.0f + Ef1;
                float n0   = fmaf(Eg0 - 1.0f, tf0, cst[ch][r]     * dig0);
                float n1   = fmaf(Eg1 - 1.0f, tf1, cst[ch][4 + r] * dig1);
                float c0   = n0 * __builtin_amdgcn_rcpf(tf0 * dig0);
                float c1   = n1 * __builtin_amdgcn_rcpf(tf1 * dig1);
                cst[ch][r] = c0; cst[ch][4 + r] = c1;
                float Ec0  = __builtin_amdgcn_exp2f(c0 * TWO_LOG2E);
                float Ec1  = __builtin_amdgcn_exp2f(c1 * TWO_LOG2E);
                float to0  = 1.0f + Eo0;
                float to1  = 1.0f + Eo1;
                float dh0  = fmaf(to0, Ec0, to0);          // (1+Eo)(1+Ec)
                float dh1  = fmaf(to1, Ec1, to1);
                hlo[ch][r] = (Ec0 - 1.0f) * __builtin_amdgcn_rcpf(dh0);
                hhi[ch][r] = (Ec1 - 1.0f) * __builtin_amdgcn_rcpf(dh1);
            }
            // pack: B-frag v[jj] = h[8q+jj] -> v[0:4]=lo units, v[4:8]=hi units
            pk[ch][0] = pack2(hlo[ch][0], hlo[ch][1]);
            pk[ch][1] = pack2(hlo[ch][2], hlo[ch][3]);
            pk[ch][2] = pack2(hhi[ch][0], hhi[ch][1]);
            pk[ch][3] = pack2(hhi[ch][2], hhi[ch][3]);
        }

        // x-MFMAs for next step, both chains — off the h critical path
        #pragma unroll
        for (int j = 0; j < 8; ++j)
            accp[0][j] = __builtin_amdgcn_mfma_f32_16x16x32_f16(Wf[j][0], xn0, bias4[j], 0, 0, 0);
        #pragma unroll
        for (int j = 0; j < 8; ++j)
            accp[1][j] = __builtin_amdgcn_mfma_f32_16x16x32_f16(Wf[j][0], xn1, bias4[j], 0, 0, 0);
    }

    // ---- epilogue: fc2 on final h (fp32 via LDS scratch over X) ----
    __syncthreads();
    #pragma unroll
    for (int ch = 0; ch < 2; ++ch)
        #pragma unroll
        for (int r = 0; r < 4; ++r) {
            *(float*)(smem + ch * 2304 + cidx * 144 + (8 * quad + r) * 4)     = hlo[ch][r];
            *(float*)(smem + ch * 2304 + cidx * 144 + (8 * quad + 4 + r) * 4) = hhi[ch][r];
        }
    __syncthreads();

    {
        int b = tid >> 2, jj = tid & 3;
        const float* fw = fc2_W + jj * 32;
        float fb = fc2_b[jj];
        #pragma unroll
        for (int ch = 0; ch < 2; ++ch) {
            const float* hrow = (const float*)(smem + ch * 2304 + b * 144);
            float s = fb;
            #pragma unroll
            for (int k = 0; k < 8; ++k) {
                float4 hv = *(const float4*)(hrow + k * 4);
                s += fw[k*4+0] * hv.x + fw[k*4+1] * hv.y
                   + fw[k*4+2] * hv.z + fw[k*4+3] * hv.w;
            }
            s = fminf(fmaxf(s, 0.0f), 1.0f);
            out[(long)blockIdx.x * 128 + ch * 64 + tid] = s;
        }
    }
}

extern "C" void kernel_launch(void* const* d_in, const int* in_sizes, int n_in,
                              void* d_out, int out_size, void* d_ws, size_t ws_size,
                              hipStream_t stream)
{
    // inputs: 0 objs(i32) 1 boxes(f32) 2 preds(i32) 3 subj(i32) 4 target(unused)
    //         5 obj_emb 6 pred_emb 7 W_ih 8 W_hh 9 b_ih 10 b_hh 11 fc2_W 12 fc2_b
    lstm_fused<<<1024, 64, LDS_BYTES, stream>>>(
        (const int*)d_in[0], (const float*)d_in[1], (const int*)d_in[2],
        (const int*)d_in[3],
        (const float*)d_in[5], (const float*)d_in[6],
        (const float*)d_in[7], (const float*)d_in[8],
        (const float*)d_in[9], (const float*)d_in[10],
        (const float*)d_in[11], (const float*)d_in[12],
        (float*)d_out);
}

// Round 10
// 132.010 us; speedup vs baseline: 1.1103x; 1.1103x over previous
//
#include <hip/hip_runtime.h>

// multi_triples_lstm v9b: v7 skeleton (4-way unit-split, 256-thr WGs, 2048 WGs,
// one exchange barrier/step) with content cuts:
//  - activations as float2 -> v_pk_{fma,add,mul}_f32 (halves full-rate ops)
//  - v_cvt_pkrtz_f16_f32 for the h pack (1 instr)  [fixed: builtin returns
//    __fp16x2, union member now uses that type]
//  - loop reordered write -> barrier -> x-MFMA -> read so the ds_read latency
//    hides under x-MFMA issue
// Shared-denominator algebra (7 trans/unit-step); scales folded into fp16
// weights: i/f/o rows * -log2e, g rows * +2log2e.
//
// LDS (dynamic):
//   X   @ 0     : 16 rows x 1040B (fp16 feats; (b,t) at b*1040 + t*32)
//   HX0 @ 16640 : 1024B (4 waves x 64 lanes x 4B packed h)
//   HX1 @ 17664 : 1024B (double buffer)
//   Z   @ 18688 : 32B zeros (x-frag quads 2,3)
//   fc2 scratch overlays X (16 rows x 144B)
#define LDS_BYTES 18720

typedef _Float16 f16x8 __attribute__((ext_vector_type(8)));
typedef __fp16   fp16x2 __attribute__((ext_vector_type(2)));
typedef float    f32x4 __attribute__((ext_vector_type(4)));
typedef float    f32x2 __attribute__((ext_vector_type(2)));

#define LOG2E     1.44269504088896f
#define TWO_LOG2E 2.88539008177793f

__global__ __launch_bounds__(256, 8)
void lstm_fused(const int* __restrict__ objs,
                const float* __restrict__ boxes,
                const int* __restrict__ preds,
                const int* __restrict__ subj,
                const float* __restrict__ obj_emb,
                const float* __restrict__ pred_emb,
                const float* __restrict__ W_ih,
                const float* __restrict__ W_hh,
                const float* __restrict__ b_ih,
                const float* __restrict__ b_hh,
                const float* __restrict__ fc2_W,
                const float* __restrict__ fc2_b,
                float* __restrict__ out)
{
    extern __shared__ char smem[];
    const int tid  = threadIdx.x;
    const int lane = tid & 63;
    const int wv   = tid >> 6;           // 0..3: which unit-pair quarter
    const int quad = lane >> 4;          // 0..3
    const int cidx = lane & 15;          // batch index
    const int XOFF = 0, HX0 = 16640, HX1 = 17664, ZOFF = 18688;

    if (tid < 8) ((int*)(smem + ZOFF))[tid] = 0;

    // ---- stage x features (fp16): 256 threads, 2 t each ----
    {
        int b  = tid >> 4;               // 0..15
        int t0 = (tid & 15) << 1;        // 0,2,...,30
        long gb = (long)blockIdx.x * 16 + b;
        int2 ov = *(const int2*)(objs  + gb * 32 + t0);
        int2 pv = *(const int2*)(preds + gb * 32 + t0);
        int2 sv = *(const int2*)(subj  + gb * 32 + t0);
        int oarr[2] = {ov.x, ov.y};
        int parr[2] = {pv.x, pv.y};
        int sarr[2] = {sv.x, sv.y};
        #pragma unroll
        for (int tt = 0; tt < 2; ++tt) {
            int t = t0 + tt;
            const float* eo = obj_emb  + oarr[tt] * 5;
            const float* ep = pred_emb + parr[tt] * 5;
            float4 bx = *(const float4*)(boxes + (gb * 32 + t) * 4);
            f16x8 lo, hi;
            lo[0]=(_Float16)eo[0]; lo[1]=(_Float16)eo[1]; lo[2]=(_Float16)eo[2];
            lo[3]=(_Float16)eo[3]; lo[4]=(_Float16)eo[4];
            lo[5]=(_Float16)ep[0]; lo[6]=(_Float16)ep[1]; lo[7]=(_Float16)ep[2];
            hi[0]=(_Float16)ep[3]; hi[1]=(_Float16)ep[4];
            hi[2]=(_Float16)(sarr[tt]==0 ? 1.0f : 0.0f);
            hi[3]=(_Float16)(sarr[tt]==1 ? 1.0f : 0.0f);
            hi[4]=(_Float16)bx.x; hi[5]=(_Float16)bx.y;
            hi[6]=(_Float16)bx.z; hi[7]=(_Float16)bx.w;
            char* dst = smem + XOFF + b * 1040 + t * 32;
            *(f16x8*)dst        = lo;
            *(f16x8*)(dst + 16) = hi;
        }
    }

    // ---- W fragments: wave wv, tile row m: unit u=8*(m>>2)+2*wv+(m&1),
    //      gate = tile*2 + ((m&3)>>1)  (0=i,1=f,2=g,3=o; canonical n=g*32+u)
    f16x8 Wf[2][2];
    f32x4 bias4[2];
    #pragma unroll
    for (int tile = 0; tile < 2; ++tile) {
        int rm   = cidx & 3;
        int u    = 8 * (cidx >> 2) + 2 * wv + (rm & 1);
        int gate = tile * 2 + (rm >> 1);
        float scale = (gate == 2) ? TWO_LOG2E : -LOG2E;
        int n = gate * 32 + u;
        #pragma unroll
        for (int ks = 0; ks < 2; ++ks) {
            f16x8 v;
            #pragma unroll
            for (int jj = 0; jj < 8; ++jj) {
                int k = ks * 32 + quad * 8 + jj;
                float val = (k < 16) ? W_ih[n * 16 + k]
                          : (k >= 32) ? W_hh[n * 32 + (k - 32)]
                          : 0.0f;
                v[jj] = (_Float16)(val * scale);
            }
            Wf[tile][ks] = v;
        }
        #pragma unroll
        for (int r = 0; r < 4; ++r) {
            int ur = 8 * quad + 2 * wv + (r & 1);
            int gr = tile * 2 + (r >> 1);
            float sc = (gr == 2) ? TWO_LOG2E : -LOG2E;
            bias4[tile][r] = (b_ih[gr * 32 + ur] + b_hh[gr * 32 + ur]) * sc;
        }
    }

    // ---- addressing ----
    const bool qlow = (quad < 2);
    int       xaddr = qlow ? (XOFF + cidx * 1040 + quad * 16) : ZOFF;
    const int xinc  = qlow ? 32 : 0;
    const int slot  = lane * 4;                      // dword slot in HX buffer

    // de-phase the 8 WGs sharing a CU
    {
        int del = (blockIdx.x * 37) & 31;
        while (del--) asm volatile("s_sleep 2" ::: "memory");
    }

    __syncthreads();   // staging visible

    // prime: x[0] MFMAs (bias rides as C); h(0)=0
    f16x8 xfrag = *(const f16x8*)(smem + xaddr); xaddr += xinc;
    f32x4 accp[2];
    #pragma unroll
    for (int tile = 0; tile < 2; ++tile)
        accp[tile] = __builtin_amdgcn_mfma_f32_16x16x32_f16(Wf[tile][0], xfrag, bias4[tile], 0, 0, 0);

    union { int i[4]; f16x8 v; } hf;
    hf.i[0] = 0; hf.i[1] = 0; hf.i[2] = 0; hf.i[3] = 0;
    const f32x2 one = {1.0f, 1.0f};
    f32x2 cstv = {0.0f, 0.0f};
    f32x2 hv = {0.0f, 0.0f};

    #pragma unroll 2
    for (int t = 0; t < 32; ++t) {
        // h-MFMAs: acc0 = {i(u0),i(u1),f(u0),f(u1)}, acc1 = {g(u0),g(u1),o(u0),o(u1)}
        f32x4 acc0 = __builtin_amdgcn_mfma_f32_16x16x32_f16(Wf[0][1], hf.v, accp[0], 0, 0, 0);
        f32x4 acc1 = __builtin_amdgcn_mfma_f32_16x16x32_f16(Wf[1][1], hf.v, accp[1], 0, 0, 0);

        // prefetch next x (t=31 reads row pad — discarded)
        f16x8 xn = *(const f16x8*)(smem + xaddr); xaddr += xinc;

        // shared-denominator activations, packed f32x2 (v_pk_* full-rate ops)
        f32x2 Ei = {__builtin_amdgcn_exp2f(acc0[0]), __builtin_amdgcn_exp2f(acc0[1])};
        f32x2 Ef = {__builtin_amdgcn_exp2f(acc0[2]), __builtin_amdgcn_exp2f(acc0[3])};
        f32x2 Eg = {__builtin_amdgcn_exp2f(acc1[0]), __builtin_amdgcn_exp2f(acc1[1])};
        f32x2 Eo = {__builtin_amdgcn_exp2f(acc1[2]), __builtin_amdgcn_exp2f(acc1[3])};

        f32x2 t1  = Ei + one;
        f32x2 dig = t1 * Eg + t1;                    // (1+Ei)(1+Eg)
        f32x2 tf  = Ef + one;
        f32x2 nn  = (Eg - one) * tf + cstv * dig;
        f32x2 den = tf * dig;
        f32x2 rde = {__builtin_amdgcn_rcpf(den.x), __builtin_amdgcn_rcpf(den.y)};
        f32x2 c   = nn * rde;
        cstv = c;
        f32x2 cl  = c * TWO_LOG2E;
        f32x2 Ec  = {__builtin_amdgcn_exp2f(cl.x), __builtin_amdgcn_exp2f(cl.y)};
        f32x2 to  = Eo + one;
        f32x2 dh  = to * Ec + to;                    // (1+Eo)(1+Ec)
        f32x2 rdh = {__builtin_amdgcn_rcpf(dh.x), __builtin_amdgcn_rcpf(dh.y)};
        hv = (Ec - one) * rdh;

        union { fp16x2 h; int i; } pku;
        pku.h = __builtin_amdgcn_cvt_pkrtz(hv.x, hv.y);
        int pk = pku.i;

        // publish own dword (= B-frag dword wv), double-buffered; barrier
        // immediately so partners' reads start ASAP; x-MFMA fills the window
        char* buf = smem + ((t & 1) ? HX1 : HX0);
        *(int*)(buf + wv * 256 + slot) = pk;
        __syncthreads();

        // x-MFMAs for next step — issue in the ds_read latency window
        accp[0] = __builtin_amdgcn_mfma_f32_16x16x32_f16(Wf[0][0], xn, bias4[0], 0, 0, 0);
        accp[1] = __builtin_amdgcn_mfma_f32_16x16x32_f16(Wf[1][0], xn, bias4[1], 0, 0, 0);

        // gather full h: dword d = units 8q+2d,8q+2d+1
        hf.i[0] = *(const int*)(buf + 0   + slot);
        hf.i[1] = *(const int*)(buf + 256 + slot);
        hf.i[2] = *(const int*)(buf + 512 + slot);
        hf.i[3] = *(const int*)(buf + 768 + slot);
    }

    // ---- epilogue: fc2 on final h (fp32 via LDS scratch over X) ----
    __syncthreads();
    {
        int u0 = 8 * quad + 2 * wv;
        *(float2*)(smem + cidx * 144 + u0 * 4) = (float2){hv.x, hv.y};
    }
    __syncthreads();

    if (tid < 64) {
        int b = tid >> 2, jj = tid & 3;
        const float* fw   = fc2_W + jj * 32;
        const float* hrow = (const float*)(smem + b * 144);
        float s = fc2_b[jj];
        #pragma unroll
        for (int k = 0; k < 8; ++k) {
            float4 hvv = *(const float4*)(hrow + k * 4);
            s += fw[k*4+0] * hvv.x + fw[k*4+1] * hvv.y
               + fw[k*4+2] * hvv.z + fw[k*4+3] * hvv.w;
        }
        s = fminf(fmaxf(s, 0.0f), 1.0f);
        out[(long)blockIdx.x * 64 + tid] = s;
    }
}

extern "C" void kernel_launch(void* const* d_in, const int* in_sizes, int n_in,
                              void* d_out, int out_size, void* d_ws, size_t ws_size,
                              hipStream_t stream)
{
    // inputs: 0 objs(i32) 1 boxes(f32) 2 preds(i32) 3 subj(i32) 4 target(unused)
    //         5 obj_emb 6 pred_emb 7 W_ih 8 W_hh 9 b_ih 10 b_hh 11 fc2_W 12 fc2_b
    lstm_fused<<<2048, 256, LDS_BYTES, stream>>>(
        (const int*)d_in[0], (const float*)d_in[1], (const int*)d_in[2],
        (const int*)d_in[3],
        (const float*)d_in[5], (const float*)d_in[6],
        (const float*)d_in[7], (const float*)d_in[8],
        (const float*)d_in[9], (const float*)d_in[10],
        (const float*)d_in[11], (const float*)d_in[12],
        (float*)d_out);
}

// Round 11
// 129.765 us; speedup vs baseline: 1.1295x; 1.0173x over previous
//
#include <hip/hip_runtime.h>

// multi_triples_lstm v10: v9b + exchange compaction and full unroll.
//  - HX layout: lane L's 4 partner dwords contiguous at L*16 -> exchange is
//    1 ds_write_b32 (L*16+wv*4, 8-way bank alias accepted) + 1 ds_read_b128
//    (contiguous, optimal) instead of 1 write + 4 reads.
//  - t-loop fully unrolled: (t&1) buffer select folds, no loop overhead.
//  - shared-denominator algebra (7 trans/unit-step), packed f32x2 full-rate,
//    cvt_pkrtz h-pack. Scales folded into fp16 weights.
//
// LDS (dynamic):
//   X   @ 0     : 16 rows x 1040B (fp16 feats; (b,t) at b*1040 + t*32)
//   HX0 @ 16640 : 1024B (64 lanes x 16B: dword d = wave d's packed h)
//   HX1 @ 17664 : 1024B (double buffer)
//   Z   @ 18688 : 32B zeros (x-frag quads 2,3)
//   fc2 scratch overlays X (16 rows x 144B)
#define LDS_BYTES 18720

typedef _Float16 f16x8 __attribute__((ext_vector_type(8)));
typedef __fp16   fp16x2 __attribute__((ext_vector_type(2)));
typedef float    f32x4 __attribute__((ext_vector_type(4)));
typedef float    f32x2 __attribute__((ext_vector_type(2)));

#define LOG2E     1.44269504088896f
#define TWO_LOG2E 2.88539008177793f

__global__ __launch_bounds__(256, 8)
void lstm_fused(const int* __restrict__ objs,
                const float* __restrict__ boxes,
                const int* __restrict__ preds,
                const int* __restrict__ subj,
                const float* __restrict__ obj_emb,
                const float* __restrict__ pred_emb,
                const float* __restrict__ W_ih,
                const float* __restrict__ W_hh,
                const float* __restrict__ b_ih,
                const float* __restrict__ b_hh,
                const float* __restrict__ fc2_W,
                const float* __restrict__ fc2_b,
                float* __restrict__ out)
{
    extern __shared__ char smem[];
    const int tid  = threadIdx.x;
    const int lane = tid & 63;
    const int wv   = tid >> 6;           // 0..3: which unit-pair quarter
    const int quad = lane >> 4;          // 0..3
    const int cidx = lane & 15;          // batch index
    const int XOFF = 0, HX0 = 16640, HX1 = 17664, ZOFF = 18688;

    if (tid < 8) ((int*)(smem + ZOFF))[tid] = 0;

    // ---- stage x features (fp16): 256 threads, 2 t each ----
    {
        int b  = tid >> 4;               // 0..15
        int t0 = (tid & 15) << 1;        // 0,2,...,30
        long gb = (long)blockIdx.x * 16 + b;
        int2 ov = *(const int2*)(objs  + gb * 32 + t0);
        int2 pv = *(const int2*)(preds + gb * 32 + t0);
        int2 sv = *(const int2*)(subj  + gb * 32 + t0);
        int oarr[2] = {ov.x, ov.y};
        int parr[2] = {pv.x, pv.y};
        int sarr[2] = {sv.x, sv.y};
        #pragma unroll
        for (int tt = 0; tt < 2; ++tt) {
            int t = t0 + tt;
            const float* eo = obj_emb  + oarr[tt] * 5;
            const float* ep = pred_emb + parr[tt] * 5;
            float4 bx = *(const float4*)(boxes + (gb * 32 + t) * 4);
            f16x8 lo, hi;
            lo[0]=(_Float16)eo[0]; lo[1]=(_Float16)eo[1]; lo[2]=(_Float16)eo[2];
            lo[3]=(_Float16)eo[3]; lo[4]=(_Float16)eo[4];
            lo[5]=(_Float16)ep[0]; lo[6]=(_Float16)ep[1]; lo[7]=(_Float16)ep[2];
            hi[0]=(_Float16)ep[3]; hi[1]=(_Float16)ep[4];
            hi[2]=(_Float16)(sarr[tt]==0 ? 1.0f : 0.0f);
            hi[3]=(_Float16)(sarr[tt]==1 ? 1.0f : 0.0f);
            hi[4]=(_Float16)bx.x; hi[5]=(_Float16)bx.y;
            hi[6]=(_Float16)bx.z; hi[7]=(_Float16)bx.w;
            char* dst = smem + XOFF + b * 1040 + t * 32;
            *(f16x8*)dst        = lo;
            *(f16x8*)(dst + 16) = hi;
        }
    }

    // ---- W fragments: wave wv, tile row m: unit u=8*(m>>2)+2*wv+(m&1),
    //      gate = tile*2 + ((m&3)>>1)  (0=i,1=f,2=g,3=o; canonical n=g*32+u)
    f16x8 Wf[2][2];
    f32x4 bias4[2];
    #pragma unroll
    for (int tile = 0; tile < 2; ++tile) {
        int rm   = cidx & 3;
        int u    = 8 * (cidx >> 2) + 2 * wv + (rm & 1);
        int gate = tile * 2 + (rm >> 1);
        float scale = (gate == 2) ? TWO_LOG2E : -LOG2E;
        int n = gate * 32 + u;
        #pragma unroll
        for (int ks = 0; ks < 2; ++ks) {
            f16x8 v;
            #pragma unroll
            for (int jj = 0; jj < 8; ++jj) {
                int k = ks * 32 + quad * 8 + jj;
                float val = (k < 16) ? W_ih[n * 16 + k]
                          : (k >= 32) ? W_hh[n * 32 + (k - 32)]
                          : 0.0f;
                v[jj] = (_Float16)(val * scale);
            }
            Wf[tile][ks] = v;
        }
        #pragma unroll
        for (int r = 0; r < 4; ++r) {
            int ur = 8 * quad + 2 * wv + (r & 1);
            int gr = tile * 2 + (r >> 1);
            float sc = (gr == 2) ? TWO_LOG2E : -LOG2E;
            bias4[tile][r] = (b_ih[gr * 32 + ur] + b_hh[gr * 32 + ur]) * sc;
        }
    }

    // ---- addressing ----
    const bool qlow = (quad < 2);
    int       xaddr = qlow ? (XOFF + cidx * 1040 + quad * 16) : ZOFF;
    const int xinc  = qlow ? 32 : 0;
    const int slot16 = lane << 4;                    // 16B slot in HX buffer
    const int wr_off = slot16 + (wv << 2);           // own dword within slot

    __syncthreads();   // staging visible

    // prime: x[0] MFMAs (bias rides as C); h(0)=0
    f16x8 xfrag = *(const f16x8*)(smem + xaddr); xaddr += xinc;
    f32x4 accp[2];
    #pragma unroll
    for (int tile = 0; tile < 2; ++tile)
        accp[tile] = __builtin_amdgcn_mfma_f32_16x16x32_f16(Wf[tile][0], xfrag, bias4[tile], 0, 0, 0);

    union { int i[4]; f16x8 v; } hf;
    hf.i[0] = 0; hf.i[1] = 0; hf.i[2] = 0; hf.i[3] = 0;
    const f32x2 one = {1.0f, 1.0f};
    f32x2 cstv = {0.0f, 0.0f};
    f32x2 hv = {0.0f, 0.0f};

    #pragma unroll
    for (int t = 0; t < 32; ++t) {
        // h-MFMAs: acc0 = {i(u0),i(u1),f(u0),f(u1)}, acc1 = {g(u0),g(u1),o(u0),o(u1)}
        f32x4 acc0 = __builtin_amdgcn_mfma_f32_16x16x32_f16(Wf[0][1], hf.v, accp[0], 0, 0, 0);
        f32x4 acc1 = __builtin_amdgcn_mfma_f32_16x16x32_f16(Wf[1][1], hf.v, accp[1], 0, 0, 0);

        // prefetch next x (t=31 reads row pad — discarded)
        f16x8 xn = *(const f16x8*)(smem + xaddr); xaddr += xinc;

        // shared-denominator activations, packed f32x2 (v_pk_* full-rate ops)
        f32x2 Ei = {__builtin_amdgcn_exp2f(acc0[0]), __builtin_amdgcn_exp2f(acc0[1])};
        f32x2 Ef = {__builtin_amdgcn_exp2f(acc0[2]), __builtin_amdgcn_exp2f(acc0[3])};
        f32x2 Eg = {__builtin_amdgcn_exp2f(acc1[0]), __builtin_amdgcn_exp2f(acc1[1])};
        f32x2 Eo = {__builtin_amdgcn_exp2f(acc1[2]), __builtin_amdgcn_exp2f(acc1[3])};

        f32x2 t1  = Ei + one;
        f32x2 dig = t1 * Eg + t1;                    // (1+Ei)(1+Eg)
        f32x2 tf  = Ef + one;
        f32x2 nn  = (Eg - one) * tf + cstv * dig;
        f32x2 den = tf * dig;
        f32x2 rde = {__builtin_amdgcn_rcpf(den.x), __builtin_amdgcn_rcpf(den.y)};
        f32x2 c   = nn * rde;
        cstv = c;
        f32x2 cl  = c * TWO_LOG2E;
        f32x2 Ec  = {__builtin_amdgcn_exp2f(cl.x), __builtin_amdgcn_exp2f(cl.y)};
        f32x2 to  = Eo + one;
        f32x2 dh  = to * Ec + to;                    // (1+Eo)(1+Ec)
        f32x2 rdh = {__builtin_amdgcn_rcpf(dh.x), __builtin_amdgcn_rcpf(dh.y)};
        hv = (Ec - one) * rdh;

        union { fp16x2 h; int i; } pku;
        pku.h = __builtin_amdgcn_cvt_pkrtz(hv.x, hv.y);

        // publish own dword into lane-contiguous slot; barrier; partners'
        // gather is ONE ds_read_b128 whose latency hides under the x-MFMAs
        char* buf = smem + ((t & 1) ? HX1 : HX0);
        *(int*)(buf + wr_off) = pku.i;
        __syncthreads();

        // x-MFMAs for next step — issue in the ds_read latency window
        accp[0] = __builtin_amdgcn_mfma_f32_16x16x32_f16(Wf[0][0], xn, bias4[0], 0, 0, 0);
        accp[1] = __builtin_amdgcn_mfma_f32_16x16x32_f16(Wf[1][0], xn, bias4[1], 0, 0, 0);

        // full h B-frag: dword d = wave d = units {8q+2d, 8q+2d+1}
        hf.v = *(const f16x8*)(buf + slot16);
    }

    // ---- epilogue: fc2 on final h (fp32 via LDS scratch over X) ----
    __syncthreads();
    {
        int u0 = 8 * quad + 2 * wv;
        *(float2*)(smem + cidx * 144 + u0 * 4) = (float2){hv.x, hv.y};
    }
    __syncthreads();

    if (tid < 64) {
        int b = tid >> 2, jj = tid & 3;
        const float* fw   = fc2_W + jj * 32;
        const float* hrow = (const float*)(smem + b * 144);
        float s = fc2_b[jj];
        #pragma unroll
        for (int k = 0; k < 8; ++k) {
            float4 hvv = *(const float4*)(hrow + k * 4);
            s += fw[k*4+0] * hvv.x + fw[k*4+1] * hvv.y
               + fw[k*4+2] * hvv.z + fw[k*4+3] * hvv.w;
        }
        s = fminf(fmaxf(s, 0.0f), 1.0f);
        out[(long)blockIdx.x * 64 + tid] = s;
    }
}

extern "C" void kernel_launch(void* const* d_in, const int* in_sizes, int n_in,
                              void* d_out, int out_size, void* d_ws, size_t ws_size,
                              hipStream_t stream)
{
    // inputs: 0 objs(i32) 1 boxes(f32) 2 preds(i32) 3 subj(i32) 4 target(unused)
    //         5 obj_emb 6 pred_emb 7 W_ih 8 W_hh 9 b_ih 10 b_hh 11 fc2_W 12 fc2_b
    lstm_fused<<<2048, 256, LDS_BYTES, stream>>>(
        (const int*)d_in[0], (const float*)d_in[1], (const int*)d_in[2],
        (const int*)d_in[3],
        (const float*)d_in[5], (const float*)d_in[6],
        (const float*)d_in[7], (const float*)d_in[8],
        (const float*)d_in[9], (const float*)d_in[10],
        (const float*)d_in[11], (const float*)d_in[12],
        (float*)d_out);
}